// Round 1
// baseline (407.416 us; speedup 1.0000x reference)
//
#include <hip/hip_runtime.h>

#define HH 512
#define WW 512
#define HWSZ (HH*WW)
#define NB 32
#define NLD 100000
#define NF 16
#define EPSV 1e-3f
#define TILE 16
#define GR (TILE+4)   // grid halo tile 20x20
#define YR (TILE+2)   // y1 tile 18x18

__global__ __launch_bounds__(256) void scatter_k(const float* __restrict__ x,
    const int* __restrict__ idx, float* __restrict__ grid) {
  int t = blockIdx.x*256 + threadIdx.x;
  if (t >= NB*NLD) return;
  int b = t / NLD;
  int i = t - b*NLD;
  atomicAdd(grid + (size_t)b*HWSZ + idx[i], x[t]);
}

__global__ __launch_bounds__(256) void gather_k(const float* __restrict__ x,
    const int* __restrict__ idx, const float* __restrict__ y, float* __restrict__ out) {
  int t = blockIdx.x*256 + threadIdx.x;
  if (t >= NB*NLD) return;
  int b = t / NLD;
  int i = t - b*NLD;
  out[t] = x[t] + y[(size_t)b*HWSZ + idx[i]];
}

__global__ __launch_bounds__(256) void conv_k(const float* __restrict__ grid,
    const float* __restrict__ w1g, const float* __restrict__ b1g,
    const float* __restrict__ gammag, const float* __restrict__ betag,
    const float* __restrict__ mmg, const float* __restrict__ mvg,
    const float* __restrict__ w2g, const float* __restrict__ b2g,
    float* __restrict__ y)
{
  __shared__ float s_grid[GR][GR];
  __shared__ __align__(16) float s_y1[YR*YR][NF];   // 18*18 x 16ch, post-BN
  __shared__ __align__(16) float s_w1[9][NF];
  __shared__ __align__(16) float s_w2[9][NF];
  __shared__ float s_b1[NF], s_bnA[NF], s_bnB[NF];

  const int lid = threadIdx.x;
  const int b = blockIdx.z;
  const int ty0 = blockIdx.y * TILE, tx0 = blockIdx.x * TILE;
  const float* gb = grid + (size_t)b*HWSZ;

  if (lid < 144) {
    int t9 = lid / NF, c = lid % NF;
    s_w1[t9][c] = w1g[lid];
    s_w2[t9][c] = w2g[lid];
  }
  if (lid >= 192 && lid < 192+NF) {
    int c = lid - 192;
    float sc = gammag[c] * rsqrtf(mvg[c] + EPSV);
    s_bnA[c] = sc;
    s_bnB[c] = betag[c] - mmg[c]*sc;
    s_b1[c] = b1g[c];
  }

  // stage grid halo tile (zero = SAME padding for conv1)
  for (int j = lid; j < GR*GR; j += 256) {
    int r = j / GR, c = j - r*GR;
    int gh = ty0 - 2 + r, gw = tx0 - 2 + c;
    float v = 0.f;
    if ((unsigned)gh < HH && (unsigned)gw < WW) v = gb[gh*WW + gw];
    s_grid[r][c] = v;
  }
  __syncthreads();

  // ---- phase A: conv1 + bias + relu + BN -> s_y1 (18x18x16) ----
  // thread owns channel-group (lid&3)*4..+3, iterates positions
  {
    const int c0 = (lid & 3) * 4;
    float rw[9][4], ra[4], rb[4], rbias[4];
    #pragma unroll
    for (int t = 0; t < 9; ++t)
      #pragma unroll
      for (int k = 0; k < 4; ++k) rw[t][k] = s_w1[t][c0+k];
    #pragma unroll
    for (int k = 0; k < 4; ++k) { ra[k]=s_bnA[c0+k]; rb[k]=s_bnB[c0+k]; rbias[k]=s_b1[c0+k]; }

    for (int p = lid >> 2; p < YR*YR; p += 64) {
      int r = p / YR, c = p - r*YR;
      // y1 image coords; OOB y1 must be ZERO (conv2's SAME padding pads
      // conv1 OUTPUT with zeros, not conv1-of-padded-grid!)
      int yh = ty0 - 1 + r, yw = tx0 - 1 + c;
      float vmask = ((unsigned)yh < HH && (unsigned)yw < WW) ? 1.f : 0.f;
      float g[9];
      #pragma unroll
      for (int dy = 0; dy < 3; ++dy)
        #pragma unroll
        for (int dx = 0; dx < 3; ++dx) g[dy*3+dx] = s_grid[r+dy][c+dx];
      float4 o;
      float* op = &o.x;
      #pragma unroll
      for (int k = 0; k < 4; ++k) {
        float a = rbias[k];
        #pragma unroll
        for (int t = 0; t < 9; ++t) a = fmaf(g[t], rw[t][k], a);
        a = fmaxf(a, 0.f);
        op[k] = vmask * fmaf(a, ra[k], rb[k]);
      }
      *(float4*)&s_y1[p][c0] = o;
    }
  }
  __syncthreads();

  // ---- phase B: conv2 16->1 + bias ----
  {
    const int ty = lid >> 4, tx = lid & 15;
    float acc = b2g[0];
    #pragma unroll
    for (int kh = 0; kh < 3; ++kh)
      #pragma unroll
      for (int kw = 0; kw < 3; ++kw) {
        const float* yp = s_y1[(ty+kh)*YR + (tx+kw)];
        const float* wp = s_w2[kh*3+kw];
        #pragma unroll
        for (int c = 0; c < NF; c += 4) {
          float4 v = *(const float4*)&yp[c];
          float4 w = *(const float4*)&wp[c];   // uniform addr -> LDS broadcast
          acc = fmaf(v.x, w.x, acc);
          acc = fmaf(v.y, w.y, acc);
          acc = fmaf(v.z, w.z, acc);
          acc = fmaf(v.w, w.w, acc);
        }
      }
    y[(size_t)b*HWSZ + (size_t)(ty0+ty)*WW + (tx0+tx)] = acc;
  }
}

extern "C" void kernel_launch(void* const* d_in, const int* in_sizes, int n_in,
                              void* d_out, int out_size, void* d_ws, size_t ws_size,
                              hipStream_t stream) {
  const float* x     = (const float*)d_in[0];
  const float* w1    = (const float*)d_in[1];
  const float* b1    = (const float*)d_in[2];
  const float* gamma = (const float*)d_in[3];
  const float* beta  = (const float*)d_in[4];
  const float* mmean = (const float*)d_in[5];
  const float* mvar  = (const float*)d_in[6];
  const float* w2    = (const float*)d_in[7];
  const float* b2    = (const float*)d_in[8];
  const int*   idx   = (const int*)d_in[9];
  float* out = (float*)d_out;

  float* grid = (float*)d_ws;                 // NB*HWSZ floats = 33.5 MB
  float* yout = grid + (size_t)NB*HWSZ;       // NB*HWSZ floats = 33.5 MB

  hipMemsetAsync(grid, 0, (size_t)NB*HWSZ*sizeof(float), stream);

  int total = NB*NLD;
  scatter_k<<<dim3((total+255)/256), dim3(256), 0, stream>>>(x, idx, grid);

  dim3 cg(WW/TILE, HH/TILE, NB);
  conv_k<<<cg, dim3(256), 0, stream>>>(grid, w1, b1, gamma, beta, mmean, mvar, w2, b2, yout);

  gather_k<<<dim3((total+255)/256), dim3(256), 0, stream>>>(x, idx, yout, out);
}

// Round 2
// 349.829 us; speedup vs baseline: 1.1646x; 1.1646x over previous
//
#include <hip/hip_runtime.h>

#define HH 512
#define WW 512
#define HWSZ (HH*WW)
#define NB 32
#define NLD 100000
#define NF 16
#define EPSV 1e-3f
#define TILE 16
#define GR (TILE+4)   // grid halo tile 20x20
#define YR (TILE+2)   // y1/proj tile 18x18
#define YRYR (YR*YR)  // 324
#define PSTR 10       // proj row stride (9 taps + 1 pad, keeps float2 align)

// sum across the 4 lanes of a DPP quad (lanes 4q..4q+3), VALU-only
__device__ __forceinline__ float quad_sum(float v) {
  int a = __builtin_amdgcn_update_dpp(0, __float_as_int(v), 0xB1, 0xF, 0xF, true); // quad_perm [1,0,3,2]
  v += __int_as_float(a);
  int b = __builtin_amdgcn_update_dpp(0, __float_as_int(v), 0x4E, 0xF, 0xF, true); // quad_perm [2,3,0,1]
  return v + __int_as_float(b);
}

__global__ __launch_bounds__(256) void scatter_k(const float* __restrict__ x,
    const int* __restrict__ idx, float* __restrict__ grid) {
  int t = blockIdx.x*256 + threadIdx.x;   // [0, 8*NLD): 4 batches per thread
  if (t >= 8*NLD) return;
  int i = t % NLD;
  int b0 = (t / NLD) * 4;
  int cell = idx[i];
  #pragma unroll
  for (int j = 0; j < 4; ++j)
    atomicAdd(grid + (size_t)(b0+j)*HWSZ + cell, x[(size_t)(b0+j)*NLD + i]);
}

__global__ __launch_bounds__(256) void gather_k(const float* __restrict__ x,
    const int* __restrict__ idx, const float* __restrict__ y, float* __restrict__ out) {
  int t = blockIdx.x*256 + threadIdx.x;   // [0, 8*NLD): 4 batches per thread
  if (t >= 8*NLD) return;
  int i = t % NLD;
  int b0 = (t / NLD) * 4;
  int cell = idx[i];
  #pragma unroll
  for (int j = 0; j < 4; ++j)
    out[(size_t)(b0+j)*NLD + i] = x[(size_t)(b0+j)*NLD + i] + y[(size_t)(b0+j)*HWSZ + cell];
}

__global__ __launch_bounds__(256) void conv_k(const float* __restrict__ grid,
    const float* __restrict__ w1g, const float* __restrict__ b1g,
    const float* __restrict__ gammag, const float* __restrict__ betag,
    const float* __restrict__ mmg, const float* __restrict__ mvg,
    const float* __restrict__ w2g, const float* __restrict__ b2g,
    float* __restrict__ y)
{
  __shared__ float s_grid[GR][GR];
  __shared__ __align__(16) float s_proj[YRYR][PSTR];  // 324 x 10 = 13 KB
  __shared__ float s_w1[9][NF];
  __shared__ float s_w2[9][NF];
  __shared__ float s_b1[NF], s_bnA[NF], s_bnB[NF];

  const int lid = threadIdx.x;
  const int b = blockIdx.z;
  const int ty0 = blockIdx.y * TILE, tx0 = blockIdx.x * TILE;
  const float* gb = grid + (size_t)b*HWSZ;

  if (lid < 144) {
    s_w1[lid/NF][lid%NF] = w1g[lid];   // (3,3,1,16) -> [t][c]
    s_w2[lid/NF][lid%NF] = w2g[lid];   // (3,3,16,1) -> [t][c]
  }
  if (lid >= 192 && lid < 192+NF) {
    int c = lid - 192;
    float sc = gammag[c] * rsqrtf(mvg[c] + EPSV);
    s_bnA[c] = sc;
    s_bnB[c] = betag[c] - mmg[c]*sc;
    s_b1[c] = b1g[c];
  }

  // stage grid halo tile (zero = SAME padding for conv1)
  for (int j = lid; j < GR*GR; j += 256) {
    int r = j / GR, c = j - r*GR;
    int gh = ty0 - 2 + r, gw = tx0 - 2 + c;
    float v = 0.f;
    if ((unsigned)gh < HH && (unsigned)gw < WW) v = gb[gh*WW + gw];
    s_grid[r][c] = v;
  }
  __syncthreads();

  // ---- phase A: conv1+relu+BN (registers) then project onto w2 taps ----
  // quad of 4 lanes owns one pixel; lane k handles channels 4k..4k+3
  {
    const int g = lid >> 2, k = lid & 3, c0 = k*4;
    float rw1[9][4], rw2[9][4], ra[4], rb[4], rbias[4];
    #pragma unroll
    for (int t = 0; t < 9; ++t)
      #pragma unroll
      for (int j = 0; j < 4; ++j) { rw1[t][j] = s_w1[t][c0+j]; rw2[t][j] = s_w2[t][c0+j]; }
    #pragma unroll
    for (int j = 0; j < 4; ++j) { ra[j]=s_bnA[c0+j]; rb[j]=s_bnB[c0+j]; rbias[j]=s_b1[c0+j]; }

    for (int p = g; p < YRYR; p += 64) {
      int r = p / YR, c = p - r*YR;
      // OOB y1 must be ZERO (conv2's SAME padding pads conv1 OUTPUT)
      int yh = ty0 - 1 + r, yw = tx0 - 1 + c;
      float vmask = ((unsigned)yh < HH && (unsigned)yw < WW) ? 1.f : 0.f;
      float gg[9];
      #pragma unroll
      for (int dy = 0; dy < 3; ++dy)
        #pragma unroll
        for (int dx = 0; dx < 3; ++dx) gg[dy*3+dx] = s_grid[r+dy][c+dx];
      float y1v[4];
      #pragma unroll
      for (int j = 0; j < 4; ++j) {
        float a = rbias[j];
        #pragma unroll
        for (int t = 0; t < 9; ++t) a = fmaf(gg[t], rw1[t][j], a);
        a = fmaxf(a, 0.f);
        y1v[j] = vmask * fmaf(a, ra[j], rb[j]);
      }
      // proj[t] = sum_c y1[c]*w2[t][c]: partial over own 4 ch, quad-reduce
      float pr[9];
      #pragma unroll
      for (int t = 0; t < 9; ++t) {
        float s =       y1v[0]*rw2[t][0];
        s = fmaf(y1v[1], rw2[t][1], s);
        s = fmaf(y1v[2], rw2[t][2], s);
        s = fmaf(y1v[3], rw2[t][3], s);
        pr[t] = quad_sum(s);
      }
      // lane k writes taps {2k,2k+1} as float2; lane 0 also writes tap 8
      float a0, a1;
      if      (k == 0) { a0 = pr[0]; a1 = pr[1]; }
      else if (k == 1) { a0 = pr[2]; a1 = pr[3]; }
      else if (k == 2) { a0 = pr[4]; a1 = pr[5]; }
      else             { a0 = pr[6]; a1 = pr[7]; }
      *(float2*)&s_proj[p][2*k] = make_float2(a0, a1);
      if (k == 0) s_proj[p][8] = pr[8];
    }
  }
  __syncthreads();

  // ---- phase B: out = b2 + sum_t proj[t] at shifted pixel; 9 scalar reads ----
  {
    const int ty = lid >> 4, tx = lid & 15;
    float acc = b2g[0];
    #pragma unroll
    for (int kh = 0; kh < 3; ++kh)
      #pragma unroll
      for (int kw = 0; kw < 3; ++kw)
        acc += s_proj[(ty+kh)*YR + (tx+kw)][kh*3+kw];
    y[(size_t)b*HWSZ + (size_t)(ty0+ty)*WW + (tx0+tx)] = acc;
  }
}

extern "C" void kernel_launch(void* const* d_in, const int* in_sizes, int n_in,
                              void* d_out, int out_size, void* d_ws, size_t ws_size,
                              hipStream_t stream) {
  const float* x     = (const float*)d_in[0];
  const float* w1    = (const float*)d_in[1];
  const float* b1    = (const float*)d_in[2];
  const float* gamma = (const float*)d_in[3];
  const float* beta  = (const float*)d_in[4];
  const float* mmean = (const float*)d_in[5];
  const float* mvar  = (const float*)d_in[6];
  const float* w2    = (const float*)d_in[7];
  const float* b2    = (const float*)d_in[8];
  const int*   idx   = (const int*)d_in[9];
  float* out = (float*)d_out;

  float* grid = (float*)d_ws;                 // 33.5 MB
  float* yout = grid + (size_t)NB*HWSZ;       // 33.5 MB

  hipMemsetAsync(grid, 0, (size_t)NB*HWSZ*sizeof(float), stream);

  int total = 8*NLD;  // 4 batches per thread
  scatter_k<<<dim3((total+255)/256), dim3(256), 0, stream>>>(x, idx, grid);

  dim3 cg(WW/TILE, HH/TILE, NB);
  conv_k<<<cg, dim3(256), 0, stream>>>(grid, w1, b1, gamma, beta, mmean, mvar, w2, b2, yout);

  gather_k<<<dim3((total+255)/256), dim3(256), 0, stream>>>(x, idx, yout, out);
}

// Round 3
// 310.984 us; speedup vs baseline: 1.3101x; 1.1249x over previous
//
#include <hip/hip_runtime.h>
#include <hip/hip_bf16.h>

#define HH 512
#define WW 512
#define HWSZ (HH*WW)
#define NB 32
#define NLD 100000
#define NF 16
#define EPSV 1e-3f
#define TILE 16
#define GR (TILE+4)    // grid halo tile 20x20
#define YR (TILE+2)    // y1/proj tile 18x18
#define YRYR (YR*YR)   // 324
#define NGRP 21        // ceil(324/16) pixel-groups for MFMA
#define PSLOTS (NGRP*16)  // 336 (rows 324..335 are scratch, never read)
#define PSTR 10

typedef __attribute__((ext_vector_type(8))) short bf16x8;
typedef __attribute__((ext_vector_type(4))) float f32x4;

static __device__ __forceinline__ short f2bf(float f) {
  __hip_bfloat16 h = __float2bfloat16(f);
  return __builtin_bit_cast(short, h);
}

// ---- XCD-affine batch mapping: b = blockIdx&31 -> XCD b%8; 4 batches (4MB
// grid) resident per XCD L2, so scatter atomics / conv reads / gather reads
// of batch b all hit the same L2 without cross-XCD line migration. ----

__global__ __launch_bounds__(256) void zero_k(float* __restrict__ grid) {
  int j = blockIdx.x;
  int b = j & 31, chunk = j >> 5;          // 256 chunks/batch
  size_t base = (size_t)b*HWSZ + (size_t)chunk*1024 + threadIdx.x*4;
  *(float4*)(grid + base) = make_float4(0.f, 0.f, 0.f, 0.f);
}

__global__ __launch_bounds__(256) void scatter_k(const float* __restrict__ x,
    const int* __restrict__ idx, float* __restrict__ grid) {
  int j = blockIdx.x;
  int b = j & 31, chunk = j >> 5;
  int i = chunk*256 + threadIdx.x;
  if (i >= NLD) return;
  atomicAdd(grid + (size_t)b*HWSZ + idx[i], x[(size_t)b*NLD + i]);
}

__global__ __launch_bounds__(256) void gather_k(const float* __restrict__ x,
    const int* __restrict__ idx, const float* __restrict__ y, float* __restrict__ out) {
  int j = blockIdx.x;
  int b = j & 31, chunk = j >> 5;
  int i = chunk*256 + threadIdx.x;
  if (i >= NLD) return;
  out[(size_t)b*NLD + i] = x[(size_t)b*NLD + i] + y[(size_t)b*HWSZ + idx[i]];
}

__global__ __launch_bounds__(256) void conv_k(const float* __restrict__ grid,
    const float* __restrict__ w1g, const float* __restrict__ b1g,
    const float* __restrict__ gammag, const float* __restrict__ betag,
    const float* __restrict__ mmg, const float* __restrict__ mvg,
    const float* __restrict__ w2g, const float* __restrict__ b2g,
    float* __restrict__ y)
{
  __shared__ float s_grid[GR][GR];
  __shared__ __align__(16) short s_y1b[PSLOTS][NF];   // y1 post-BN, bf16
  __shared__ float s_proj[PSLOTS][PSTR];
  __shared__ float s_w1[9][NF];
  __shared__ float s_b1[NF], s_bnA[NF], s_bnB[NF];

  const int lid = threadIdx.x;
  const int j = blockIdx.x;
  const int b = j & 31;                    // XCD-affine batch
  const int tile = j >> 5;
  const int ty0 = (tile >> 5) * TILE, tx0 = (tile & 31) * TILE;
  const float* gb = grid + (size_t)b*HWSZ;

  // A-fragment for proj MFMA: A[m=tap][k=ch], lane l holds m=l&15,
  // k=(l>>4)*8+jj (mfma_f32_16x16x32_bf16 A-layout). Constant per kernel.
  const int l = lid & 63;
  bf16x8 afrag;
  #pragma unroll
  for (int jj = 0; jj < 8; ++jj) {
    int m = l & 15, c = (l >> 4)*8 + jj;
    float wv = (m < 9 && c < NF) ? w2g[m*NF + c] : 0.f;
    afrag[jj] = f2bf(wv);
  }

  if (lid < 144) s_w1[lid/NF][lid%NF] = w1g[lid];
  if (lid >= 192 && lid < 192+NF) {
    int c = lid - 192;
    float sc = gammag[c] * rsqrtf(mvg[c] + EPSV);
    s_bnA[c] = sc;
    s_bnB[c] = betag[c] - mmg[c]*sc;
    s_b1[c] = b1g[c];
  }

  for (int q = lid; q < GR*GR; q += 256) {
    int r = q / GR, c = q - r*GR;
    int gh = ty0 - 2 + r, gw = tx0 - 2 + c;
    float v = 0.f;
    if ((unsigned)gh < HH && (unsigned)gw < WW) v = gb[gh*WW + gw];
    s_grid[r][c] = v;
  }
  __syncthreads();

  // ---- phase A: conv1+relu+BN (fp32, quad-split channels) -> s_y1b bf16 ----
  {
    const int g = lid >> 2, k = lid & 3, c0 = k*4;
    float rw1[9][4], ra[4], rb[4], rbias[4];
    #pragma unroll
    for (int t = 0; t < 9; ++t)
      #pragma unroll
      for (int jj = 0; jj < 4; ++jj) rw1[t][jj] = s_w1[t][c0+jj];
    #pragma unroll
    for (int jj = 0; jj < 4; ++jj) { ra[jj]=s_bnA[c0+jj]; rb[jj]=s_bnB[c0+jj]; rbias[jj]=s_b1[c0+jj]; }

    for (int p = g; p < YRYR; p += 64) {
      int r = p / YR, c = p - r*YR;
      int yh = ty0 - 1 + r, yw = tx0 - 1 + c;
      float vmask = ((unsigned)yh < HH && (unsigned)yw < WW) ? 1.f : 0.f;
      float gg[9];
      #pragma unroll
      for (int dy = 0; dy < 3; ++dy)
        #pragma unroll
        for (int dx = 0; dx < 3; ++dx) gg[dy*3+dx] = s_grid[r+dy][c+dx];
      short4 hv;
      short* hp = (short*)&hv;
      #pragma unroll
      for (int jj = 0; jj < 4; ++jj) {
        float a = rbias[jj];
        #pragma unroll
        for (int t = 0; t < 9; ++t) a = fmaf(gg[t], rw1[t][jj], a);
        a = fmaxf(a, 0.f);
        hp[jj] = f2bf(vmask * fmaf(a, ra[jj], rb[jj]));  // OOB y1 -> 0
      }
      *(short4*)&s_y1b[p][c0] = hv;
    }
  }
  __syncthreads();

  // ---- phase P: proj[t][p] = sum_c w2[t][c]*y1[p][c] via one MFMA / 16 px ----
  {
    const int wid = lid >> 6;
    for (int grp = wid; grp < NGRP; grp += 4) {
      int p = grp*16 + (l & 15);
      bf16x8 bfrag = {0,0,0,0,0,0,0,0};     // B[k=ch][n=px]: k=(l>>4)*8+jj
      if (l < 32) bfrag = *(const bf16x8*)&s_y1b[p][(l >> 4)*8];
      f32x4 d = {0.f,0.f,0.f,0.f};
      d = __builtin_amdgcn_mfma_f32_16x16x32_bf16(afrag, bfrag, d, 0, 0, 0);
      #pragma unroll
      for (int r4 = 0; r4 < 4; ++r4) {
        int t = (l >> 4)*4 + r4;            // C: col=lane&15, row=(lane>>4)*4+reg
        if (t < 9) s_proj[p][t] = d[r4];
      }
    }
  }
  __syncthreads();

  // ---- phase B: out = b2 + sum_t proj[t] at shifted pixel ----
  {
    const int ty = lid >> 4, tx = lid & 15;
    float acc = b2g[0];
    #pragma unroll
    for (int kh = 0; kh < 3; ++kh)
      #pragma unroll
      for (int kw = 0; kw < 3; ++kw)
        acc += s_proj[(ty+kh)*YR + (tx+kw)][kh*3+kw];
    y[(size_t)b*HWSZ + (size_t)(ty0+ty)*WW + (tx0+tx)] = acc;
  }
}

extern "C" void kernel_launch(void* const* d_in, const int* in_sizes, int n_in,
                              void* d_out, int out_size, void* d_ws, size_t ws_size,
                              hipStream_t stream) {
  const float* x     = (const float*)d_in[0];
  const float* w1    = (const float*)d_in[1];
  const float* b1    = (const float*)d_in[2];
  const float* gamma = (const float*)d_in[3];
  const float* beta  = (const float*)d_in[4];
  const float* mmean = (const float*)d_in[5];
  const float* mvar  = (const float*)d_in[6];
  const float* w2    = (const float*)d_in[7];
  const float* b2    = (const float*)d_in[8];
  const int*   idx   = (const int*)d_in[9];
  float* out = (float*)d_out;

  float* grid = (float*)d_ws;
  float* yout = grid + (size_t)NB*HWSZ;

  zero_k<<<dim3(32*256), dim3(256), 0, stream>>>(grid);

  int sblocks = 32 * ((NLD + 255) / 256);   // 12512, b = blockIdx&31
  scatter_k<<<dim3(sblocks), dim3(256), 0, stream>>>(x, idx, grid);

  conv_k<<<dim3(32 * (HH/TILE) * (WW/TILE)), dim3(256), 0, stream>>>(
      grid, w1, b1, gamma, beta, mmean, mvar, w2, b2, yout);

  gather_k<<<dim3(sblocks), dim3(256), 0, stream>>>(x, idx, yout, out);
}